// Round 15
// baseline (450.254 us; speedup 1.0000x reference)
//
#include <hip/hip_runtime.h>

// MoE top-2 of 8 experts. T=4096, H=1024, F=4096.
// prep(W transpose/cvt + zero xg/ctrl) -> router -> wave scan ->
// assign(wave-aggregated routing) -> gcopy -> 8-phase grouped GEMM1(relu) ->
// 8-phase grouped GEMM2 -> combine.
// GEMM: 128x128, BK=64, 4 waves, 2 blocks/CU, 8-phase quadrant interleave,
// counted vmcnt(2), region-death-derived staging.  r14 bug: quadrant derived
// from literal Q (4..7 -> OOB rows + acc[..][4..6]); fixed with (Q>>1)&1.
#define T_TOK 4096
#define H_DIM 1024
#define F_DIM 4096
#define E_NUM 8
#define R_TOT 8192
#define NT_MAX 72
#define R_CAP (NT_MAX * 128)   // 9216 rows

typedef short bf16x8 __attribute__((ext_vector_type(8)));
typedef float f32x4 __attribute__((ext_vector_type(4)));

__device__ inline unsigned short f2bf(float f) {   // RNE f32 -> bf16
  unsigned int u = __builtin_bit_cast(unsigned int, f);
  return (unsigned short)((u + 0x7FFFu + ((u >> 16) & 1u)) >> 16);
}

__device__ inline void async16(const void* g, void* l) {
  __builtin_amdgcn_global_load_lds((const __attribute__((address_space(1))) void*)g,
                                   (__attribute__((address_space(3))) void*)l, 16, 0, 0);
}

// ------- prep: W transpose/cvt 64x64 tiles (r13-proven) + zero xg/ctrl --------
__global__ __launch_bounds__(256) void prep_k(
    const float* __restrict__ W1, const float* __restrict__ W2,
    unsigned short* __restrict__ WT1, unsigned short* __restrict__ WT2,
    unsigned short* __restrict__ xg, int* __restrict__ ctrl) {
  int bid = blockIdx.x;
  if (bid >= 16384) {
    int z = bid - 16384;
    if (z < 576) {
      uint4* p = (uint4*)((char*)xg + (size_t)z * 32768) + threadIdx.x * 8;
      uint4 zz = make_uint4(0, 0, 0, 0);
#pragma unroll
      for (int j = 0; j < 8; j++) p[j] = zz;
    } else {
      for (int i = threadIdx.x; i < 1024; i += 256) ctrl[i] = 0;
    }
    return;
  }
  size_t mat = (size_t)H_DIM * F_DIM;
  const float* in; unsigned short* out; int R, C, c0, r0;
  if (bid < 8192) {
    int e = bid >> 10, t = bid & 1023;
    in = W1 + e * mat; out = WT1 + e * mat; R = H_DIM; C = F_DIM;
    c0 = (t & 63) * 64; r0 = (t >> 6) * 64;
  } else {
    int e = (bid - 8192) >> 10, t = bid & 1023;
    in = W2 + e * mat; out = WT2 + e * mat; R = F_DIM; C = H_DIM;
    c0 = (t & 15) * 64; r0 = (t >> 4) * 64;
  }
  __shared__ float tile[64][65];
  int tr = threadIdx.x >> 4, tc = (threadIdx.x & 15) * 4;
#pragma unroll
  for (int p = 0; p < 4; p++) {
    int r = tr + p * 16;
    float4 v = *(const float4*)(in + (size_t)(r0 + r) * C + c0 + tc);
    tile[r][tc + 0] = v.x; tile[r][tc + 1] = v.y;
    tile[r][tc + 2] = v.z; tile[r][tc + 3] = v.w;
  }
  __syncthreads();
  int col = threadIdx.x >> 2;
  int rb  = (threadIdx.x & 3) * 8;
  unsigned short* ob = out + (size_t)(c0 + col) * R + r0;
#pragma unroll
  for (int j = 0; j < 2; j++) {
    int r8 = rb + j * 32;
    uint4 o;
    o.x = (unsigned int)f2bf(tile[r8 + 0][col]) | ((unsigned int)f2bf(tile[r8 + 1][col]) << 16);
    o.y = (unsigned int)f2bf(tile[r8 + 2][col]) | ((unsigned int)f2bf(tile[r8 + 3][col]) << 16);
    o.z = (unsigned int)f2bf(tile[r8 + 4][col]) | ((unsigned int)f2bf(tile[r8 + 5][col]) << 16);
    o.w = (unsigned int)f2bf(tile[r8 + 6][col]) | ((unsigned int)f2bf(tile[r8 + 7][col]) << 16);
    *(uint4*)(ob + r8) = o;
  }
}

// ---------------- router ------------------------------------------------------
__global__ __launch_bounds__(256) void router_k(
    const float* __restrict__ x, const float* __restrict__ Wr,
    const float* __restrict__ br, int* __restrict__ ctrl,
    int* __restrict__ t2i, float* __restrict__ t2w) {
  int lane = threadIdx.x & 63;
  int wid  = threadIdx.x >> 6;
  int t = blockIdx.x * 4 + wid;
  const float* xr = x + (size_t)t * H_DIM;
  double acc[E_NUM];
#pragma unroll
  for (int e = 0; e < E_NUM; e++) acc[e] = 0.0;
  for (int i = lane; i < H_DIM; i += 64) {
    float xv = xr[i];
    const float* wr = Wr + (size_t)i * E_NUM;
    float4 w0 = *(const float4*)wr;
    float4 w1 = *(const float4*)(wr + 4);
    acc[0] += (double)xv * w0.x; acc[1] += (double)xv * w0.y;
    acc[2] += (double)xv * w0.z; acc[3] += (double)xv * w0.w;
    acc[4] += (double)xv * w1.x; acc[5] += (double)xv * w1.y;
    acc[6] += (double)xv * w1.z; acc[7] += (double)xv * w1.w;
  }
#pragma unroll
  for (int e = 0; e < E_NUM; e++) {
    double v = acc[e];
    for (int off = 32; off > 0; off >>= 1) v += __shfl_down(v, off);
    acc[e] = v;
  }
  if (lane == 0) {
    float l[E_NUM];
#pragma unroll
    for (int e = 0; e < E_NUM; e++) l[e] = (float)acc[e] + br[e];
    int ia = 0; float la = l[0];
#pragma unroll
    for (int e = 1; e < E_NUM; e++) if (l[e] > la) { la = l[e]; ia = e; }
    int ib = -1; float lb = -3.4e38f;
#pragma unroll
    for (int e = 0; e < E_NUM; e++) if (e != ia && l[e] > lb) { lb = l[e]; ib = e; }
    float w0 = 1.f / (1.f + __expf(lb - la));
    float w1 = 1.f - w0;
    t2i[2 * t] = ia; t2i[2 * t + 1] = ib;
    t2w[2 * t] = w0; t2w[2 * t + 1] = w1;
    atomicAdd(&ctrl[ia], 1);
    atomicAdd(&ctrl[ib], 1);
  }
}

// ------- scan (1 wave): 128-aligned offsets + tile table (<=72 tiles) ---------
__global__ void scan_k(int* ctrl) {
  int lane = threadIdx.x;
  int c = (lane < 8) ? ctrl[lane] : 0;
  int tiles = (c + 127) >> 7;
  int x = tiles;
  for (int d = 1; d < 8; d <<= 1) {
    int y = __shfl_up(x, d);
    if (lane >= d) x += y;
  }
  int excl = x - tiles;
  if (lane < 8) {
    ctrl[8 + lane]  = excl * 128;
    ctrl[17 + lane] = excl * 128;
  }
  int tot = __shfl(x, 7);
  if (lane == 0) { ctrl[25] = tot; ctrl[16] = tot * 128; }
  int ex[8], tl[8];
#pragma unroll
  for (int e = 0; e < 8; e++) { ex[e] = __shfl(excl, e); tl[e] = __shfl(tiles, e); }
  for (int i = lane; i < tot; i += 64) {
    int myE = 0;
#pragma unroll
    for (int e = 0; e < 8; e++) if (i >= ex[e] && i < ex[e] + tl[e]) myE = e;
    ctrl[32 + 2 * i] = myE;
    ctrl[33 + 2 * i] = i * 128;
  }
}

// ------- assign: wave-aggregated routing (8 atomics/wave) ---------------------
__global__ __launch_bounds__(256) void assign_k(
    const int* __restrict__ t2i, int* __restrict__ ctrl, int* __restrict__ row_map) {
  int g = blockIdx.x * 256 + threadIdx.x;
  int lane = threadIdx.x & 63;
  int e = t2i[g];
  int row = 0;
#pragma unroll
  for (int ee = 0; ee < E_NUM; ee++) {
    unsigned long long mask = __ballot(e == ee);
    if (e == ee) {
      int leader = __ffsll((long long)mask) - 1;
      int cnt = __popcll(mask);
      int rank = __popcll(mask & ((lane == 63) ? ~0ull >> 1 << 1 >> 1 | ((1ull << 63) - 1) & ((1ull << lane) - 1) : ((1ull << lane) - 1)));
      int base = 0;
      if (lane == leader) base = atomicAdd(&ctrl[17 + ee], cnt);
      base = __shfl(base, leader);
      row = base + rank;
    }
  }
  row_map[g] = row;
}

// ---------------- gcopy: x row -> bf16 row at row_map position ----------------
__global__ __launch_bounds__(128) void gcopy_k(
    const float* __restrict__ x, const int* __restrict__ row_map,
    unsigned short* __restrict__ xg) {
  int bid = blockIdx.x;
  int row = row_map[bid];
  int t = bid >> 1;
  const float* src = x + (size_t)t * H_DIM + threadIdx.x * 8;
  unsigned short* dst = xg + (size_t)row * H_DIM + threadIdx.x * 8;
  float4 v0 = *(const float4*)src;
  float4 v1 = *(const float4*)(src + 4);
  uint4 o;
  o.x = (unsigned int)f2bf(v0.x) | ((unsigned int)f2bf(v0.y) << 16);
  o.y = (unsigned int)f2bf(v0.z) | ((unsigned int)f2bf(v0.w) << 16);
  o.z = (unsigned int)f2bf(v1.x) | ((unsigned int)f2bf(v1.y) << 16);
  o.w = (unsigned int)f2bf(v1.z) | ((unsigned int)f2bf(v1.w) << 16);
  *(uint4*)dst = o;
}

// ======= 8-phase grouped BT GEMM: 128x128, BK=64, 4 waves, 2 blocks/CU ========
// LDS (64KB): buf0.A[0,16K) buf0.B[16K,32K) buf1.A[32K,48K) buf1.B[48K,64K);
// each [128][64]bf16, XOR-swizzled octets: unit = row*8 + (koct^(row&7)).
// Iteration i computes tiles u0=2i (buf0, phases 0-3) and u1=2i+1 (buf1, 4-7).
// Phase q computes quadrant (rows (q&1)*32, cols ((q>>1)&1)*32) of the wave's
// 64x64 output: 8 ds_read_b128 + 2 quarter-stages + 8 MFMA.
// Staging by region death: p0:buf1.Aq1,3(u1) p1:buf1.Bq0,1 p2:buf1.Bq2,3
// p3:buf0.Aq0,2(u2)+vmcnt(2) p4:buf0.Aq1,3 p5:buf0.Bq0,1 p6:buf0.Bq2,3
// p7:buf1.Aq0,2(u3)+vmcnt(2).  vmcnt never 0; 2 loads stay in flight.
#define BAR() do { __builtin_amdgcn_sched_barrier(0); \
                   __builtin_amdgcn_s_barrier(); \
                   __builtin_amdgcn_sched_barrier(0); } while (0)

#define STG(gbase, kt, ebase, c) \
  async16((gbase) + (size_t)((c) * 32 + srcRow) * Kstr + (kt) + srcK8, \
          lds + (ebase) + (c) * 2048 + tid * 8)

#define LDU(ebase, row, koct) \
  (*(const bf16x8*)(lds + (ebase) + (((row) * 8 + ((koct) ^ ((row) & 7))) * 8)))

#define MF(A, B, C) __builtin_amdgcn_mfma_f32_16x16x32_bf16(A, B, C, 0, 0, 0)

#define PHASE(Q, RB, G, EB, C0, C1, KT, VM) \
  { \
    const int qr = (Q) & 1, qc = ((Q) >> 1) & 1; \
    const int arow = wm * 64 + qr * 32 + lr; \
    const int brow = wn * 64 + qc * 32 + lr; \
    bf16x8 aA = LDU((RB), arow, klane); \
    bf16x8 aB = LDU((RB), arow, 4 + klane); \
    bf16x8 aC = LDU((RB), arow + 16, klane); \
    bf16x8 aD = LDU((RB), arow + 16, 4 + klane); \
    bf16x8 bA = LDU((RB) + 8192, brow, klane); \
    bf16x8 bB = LDU((RB) + 8192, brow, 4 + klane); \
    bf16x8 bC = LDU((RB) + 8192, brow + 16, klane); \
    bf16x8 bD = LDU((RB) + 8192, brow + 16, 4 + klane); \
    STG((G), (KT), (EB), (C0)); \
    STG((G), (KT), (EB), (C1)); \
    BAR(); \
    asm volatile("s_waitcnt lgkmcnt(0)" ::: "memory"); \
    __builtin_amdgcn_sched_barrier(0); \
    __builtin_amdgcn_s_setprio(1); \
    { const int mi = qr * 2, ni = qc * 2; \
      acc[mi][ni]         = MF(aA, bA, acc[mi][ni]); \
      acc[mi][ni]         = MF(aB, bB, acc[mi][ni]); \
      acc[mi][ni + 1]     = MF(aA, bC, acc[mi][ni + 1]); \
      acc[mi][ni + 1]     = MF(aB, bD, acc[mi][ni + 1]); \
      acc[mi + 1][ni]     = MF(aC, bA, acc[mi + 1][ni]); \
      acc[mi + 1][ni]     = MF(aD, bB, acc[mi + 1][ni]); \
      acc[mi + 1][ni + 1] = MF(aC, bC, acc[mi + 1][ni + 1]); \
      acc[mi + 1][ni + 1] = MF(aD, bD, acc[mi + 1][ni + 1]); } \
    __builtin_amdgcn_s_setprio(0); \
    if (VM) { asm volatile("s_waitcnt vmcnt(2)" ::: "memory"); } \
    BAR(); \
  }

template <int MAP, bool RELU, bool OUTF32>
__global__ __launch_bounds__(256, 2) void gemm8p_k(
    const int* __restrict__ ctrl, const unsigned short* __restrict__ A,
    const unsigned short* __restrict__ Bw, const float* __restrict__ bias,
    void* __restrict__ Cout, int Kstr, int N) {
  __shared__ unsigned short lds[32768];   // 64 KiB -> 2 blocks/CU
  const int bid = blockIdx.x;
  int rt, bx;
  if (MAP == 1) {       // 2304 blocks: XCD chunk q=288; rt-major
    int wg = (bid & 7) * 288 + (bid >> 3);
    rt = wg >> 5; bx = wg & 31;
  } else {              // 576 blocks: XCD chunk q=72
    int wg = (bid & 7) * 72 + (bid >> 3);
    rt = wg >> 3; bx = wg & 7;
  }
  if (rt >= ctrl[25]) return;
  const int e    = ctrl[32 + 2 * rt];
  const int row0 = ctrl[33 + 2 * rt];
  const unsigned short* Ae = A + (size_t)row0 * Kstr;
  const unsigned short* Be = Bw + (size_t)e * ((size_t)N * Kstr) + (size_t)bx * 128 * Kstr;
  const int tid = threadIdx.x, lane = tid & 63;
  const int wid = tid >> 6, wm = wid >> 1, wn = wid & 1;
  const int lr = lane & 15, klane = lane >> 4;
  const int srcRow = tid >> 3;                          // 0..31 within quarter
  const int srcK8  = ((tid & 7) ^ (srcRow & 7)) * 8;    // pre-swizzled octet
  const int NT = Kstr >> 6;       // even (K=1024 or 4096)
  const int NI = NT >> 1;

  f32x4 acc[4][4];
  f32x4 zero4 = {0.f, 0.f, 0.f, 0.f};
#pragma unroll
  for (int m = 0; m < 4; m++)
#pragma unroll
    for (int n = 0; n < 4; n++) acc[m][n] = zero4;

  // prologue: tile0 (8 quarters -> buf0) + tile1 Aq0,Aq2 -> buf1; vmcnt(2)
  {
    STG(Ae, 0, 0, 0); STG(Ae, 0, 0, 1); STG(Ae, 0, 0, 2); STG(Ae, 0, 0, 3);
    STG(Be, 0, 8192, 0); STG(Be, 0, 8192, 1); STG(Be, 0, 8192, 2); STG(Be, 0, 8192, 3);
    STG(Ae, 64, 16384, 0); STG(Ae, 64, 16384, 2);
    asm volatile("s_waitcnt vmcnt(2)" ::: "memory");
    BAR();
  }

  for (int i = 0; i < NI; i++) {
    const int kt1 = (2 * i + 1) * 64;
    const int kt2 = min(2 * i + 2, NT - 1) * 64;
    const int kt3 = min(2 * i + 3, NT - 1) * 64;
    PHASE(0, 0,     Ae, 16384, 1, 3, kt1, 0)
    PHASE(1, 0,     Be, 24576, 0, 1, kt1, 0)
    PHASE(2, 0,     Be, 24576, 2, 3, kt1, 0)
    PHASE(3, 0,     Ae, 0,     0, 2, kt2, 1)
    PHASE(4, 16384, Ae, 0,     1, 3, kt2, 0)
    PHASE(5, 16384, Be, 8192,  0, 1, kt2, 0)
    PHASE(6, 16384, Be, 8192,  2, 3, kt2, 0)
    PHASE(7, 16384, Ae, 16384, 0, 2, kt3, 1)
  }

  // ---------------- epilogue: plain stores -------------------------------------
  const int n0 = bx * 128;
  const float* be = bias + (size_t)e * N;
#pragma unroll
  for (int m = 0; m < 4; m++) {
#pragma unroll
    for (int q2 = 0; q2 < 4; q2++) {
      size_t ro = (size_t)(row0 + wm * 64 + m * 16 + (lane >> 4) * 4 + q2) * N;
#pragma unroll
      for (int n = 0; n < 4; n++) {
        int col = n0 + wn * 64 + n * 16 + lr;
        float v = acc[m][n][q2] + be[col];
        if (RELU) v = fmaxf(v, 0.f);
        if (OUTF32) ((float*)Cout)[ro + col] = v;
        else ((unsigned short*)Cout)[ro + col] = f2bf(v);
      }
    }
  }
}

// ---------------- combine: out[t] = w0*y[r0] + w1*y[r1] ----------------------
__global__ __launch_bounds__(256) void combine_k(
    const float* __restrict__ y, const int* __restrict__ row_map,
    const float* __restrict__ t2w, float* __restrict__ out) {
  int t = blockIdx.x;
  int i = threadIdx.x * 4;
  int r0 = row_map[2 * t], r1 = row_map[2 * t + 1];
  float w0 = t2w[2 * t], w1 = t2w[2 * t + 1];
  float4 a = *(const float4*)(y + (size_t)r0 * H_DIM + i);
  float4 b = *(const float4*)(y + (size_t)r1 * H_DIM + i);
  float4 o;
  o.x = w0 * a.x + w1 * b.x;
  o.y = w0 * a.y + w1 * b.y;
  o.z = w0 * a.z + w1 * b.z;
  o.w = w0 * a.w + w1 * b.w;
  *(float4*)(out + (size_t)t * H_DIM + i) = o;
}

extern "C" void kernel_launch(void* const* d_in, const int* in_sizes, int n_in,
                              void* d_out, int out_size, void* d_ws, size_t ws_size,
                              hipStream_t stream) {
  const float* x  = (const float*)d_in[0];
  const float* Wr = (const float*)d_in[1];
  const float* br = (const float*)d_in[2];
  const float* W1 = (const float*)d_in[3];
  const float* b1 = (const float*)d_in[4];
  const float* W2 = (const float*)d_in[5];
  const float* b2 = (const float*)d_in[6];
  float* out = (float*)d_out;

  char* ws = (char*)d_ws;
  int*   ctrl    = (int*)ws;
  int*   t2i     = (int*)(ws + 4096);
  float* t2w     = (float*)(ws + 4096 + 32768);
  int*   row_map = (int*)(ws + 4096 + 65536);
  size_t off = (size_t)1 << 20;
  unsigned short* WT1 = (unsigned short*)(ws + off); off += (size_t)E_NUM * F_DIM * H_DIM * 2;
  unsigned short* WT2 = (unsigned short*)(ws + off); off += (size_t)E_NUM * H_DIM * F_DIM * 2;
  unsigned short* xg  = (unsigned short*)(ws + off); off += (size_t)R_CAP * H_DIM * 2;
  unsigned short* hb  = (unsigned short*)(ws + off); off += (size_t)R_CAP * F_DIM * 2;
  float*          yb  = (float*)(ws + off);          off += (size_t)R_CAP * H_DIM * 4;

  if (ws_size < off) {
    hipMemsetAsync(d_out, 0, (size_t)out_size * 4, stream);
    return;
  }

  prep_k<<<dim3(16961), 256, 0, stream>>>(W1, W2, WT1, WT2, xg, ctrl);
  router_k<<<dim3(T_TOK / 4), 256, 0, stream>>>(x, Wr, br, ctrl, t2i, t2w);
  scan_k<<<dim3(1), 64, 0, stream>>>(ctrl);
  assign_k<<<dim3(R_TOT / 256), 256, 0, stream>>>(t2i, ctrl, row_map);
  gcopy_k<<<dim3(R_TOT), 128, 0, stream>>>(x, row_map, xg);
  gemm8p_k<1, true, false><<<dim3(2304), 256, 0, stream>>>(
      ctrl, xg, WT1, b1, hb, H_DIM, F_DIM);
  gemm8p_k<2, false, true><<<dim3(576), 256, 0, stream>>>(
      ctrl, hb, WT2, b2, yb, F_DIM, H_DIM);
  combine_k<<<dim3(T_TOK), 256, 0, stream>>>(yb, row_map, t2w, out);
}

// Round 16
// 405.066 us; speedup vs baseline: 1.1116x; 1.1116x over previous
//
#include <hip/hip_runtime.h>

// MoE top-2 of 8 experts. T=4096, H=1024, F=4096.
// memset(ctrl) -> prep+router (merged: W transpose/cvt || routing) -> scan ->
// assign(wave-aggregated) -> gcopy -> GEMM1(relu) -> GEMM2 -> combine.
// GEMM: r13's 128x128/BK64/4-wave/2-blocks-per-CU 2-phase loop — PARKED:
// five restructurings (8-phase 256^2, K-split, XCD pin, supertile, 8-phase
// quadrant) were null or regressed; ~115us = LDS-traffic+fence bound.
// xg pad rows NOT zeroed: garbage stays in pad rows, never read by combine.
#define T_TOK 4096
#define H_DIM 1024
#define F_DIM 4096
#define E_NUM 8
#define R_TOT 8192
#define NT_MAX 72
#define R_CAP (NT_MAX * 128)   // 9216 rows

typedef short bf16x8 __attribute__((ext_vector_type(8)));
typedef float f32x4 __attribute__((ext_vector_type(4)));

__device__ inline unsigned short f2bf(float f) {   // RNE f32 -> bf16
  unsigned int u = __builtin_bit_cast(unsigned int, f);
  return (unsigned short)((u + 0x7FFFu + ((u >> 16) & 1u)) >> 16);
}

__device__ inline void async16(const void* g, void* l) {
  __builtin_amdgcn_global_load_lds((const __attribute__((address_space(1))) void*)g,
                                   (__attribute__((address_space(3))) void*)l, 16, 0, 0);
}

// ------- prep+router merged ----------------------------------------------------
// bid<8192:   W1 transpose tiles; bid<16384: W2; bid>=16384: router (4 tok/blk).
// Transpose: fp32 tile[64][65], conflict-free both passes (r13-proven).
// Router independent of transpose; ctrl zeroed by memset BEFORE this launch.
__global__ __launch_bounds__(256) void prep_router_k(
    const float* __restrict__ W1, const float* __restrict__ W2,
    unsigned short* __restrict__ WT1, unsigned short* __restrict__ WT2,
    const float* __restrict__ x, const float* __restrict__ Wr,
    const float* __restrict__ br, int* __restrict__ ctrl,
    int* __restrict__ t2i, float* __restrict__ t2w) {
  int bid = blockIdx.x;
  if (bid >= 16384) {
    // ---------------- router path ----------------
    int lane = threadIdx.x & 63;
    int wid  = threadIdx.x >> 6;
    int t = (bid - 16384) * 4 + wid;
    const float* xr = x + (size_t)t * H_DIM;
    double acc[E_NUM];
#pragma unroll
    for (int e = 0; e < E_NUM; e++) acc[e] = 0.0;
    for (int i = lane; i < H_DIM; i += 64) {
      float xv = xr[i];
      const float* wr = Wr + (size_t)i * E_NUM;
      float4 w0 = *(const float4*)wr;
      float4 w1 = *(const float4*)(wr + 4);
      acc[0] += (double)xv * w0.x; acc[1] += (double)xv * w0.y;
      acc[2] += (double)xv * w0.z; acc[3] += (double)xv * w0.w;
      acc[4] += (double)xv * w1.x; acc[5] += (double)xv * w1.y;
      acc[6] += (double)xv * w1.z; acc[7] += (double)xv * w1.w;
    }
#pragma unroll
    for (int e = 0; e < E_NUM; e++) {
      double v = acc[e];
      for (int off = 32; off > 0; off >>= 1) v += __shfl_down(v, off);
      acc[e] = v;
    }
    if (lane == 0) {
      float l[E_NUM];
#pragma unroll
      for (int e = 0; e < E_NUM; e++) l[e] = (float)acc[e] + br[e];
      int ia = 0; float la = l[0];
#pragma unroll
      for (int e = 1; e < E_NUM; e++) if (l[e] > la) { la = l[e]; ia = e; }
      int ib = -1; float lb = -3.4e38f;
#pragma unroll
      for (int e = 0; e < E_NUM; e++) if (e != ia && l[e] > lb) { lb = l[e]; ib = e; }
      float w0 = 1.f / (1.f + __expf(lb - la));
      float w1 = 1.f - w0;
      t2i[2 * t] = ia; t2i[2 * t + 1] = ib;
      t2w[2 * t] = w0; t2w[2 * t + 1] = w1;
      atomicAdd(&ctrl[ia], 1);
      atomicAdd(&ctrl[ib], 1);
    }
    return;
  }
  // ---------------- transpose path ----------------
  size_t mat = (size_t)H_DIM * F_DIM;
  const float* in; unsigned short* out; int R, C, c0, r0;
  if (bid < 8192) {
    int e = bid >> 10, t = bid & 1023;
    in = W1 + e * mat; out = WT1 + e * mat; R = H_DIM; C = F_DIM;
    c0 = (t & 63) * 64; r0 = (t >> 6) * 64;
  } else {
    int e = (bid - 8192) >> 10, t = bid & 1023;
    in = W2 + e * mat; out = WT2 + e * mat; R = F_DIM; C = H_DIM;
    c0 = (t & 15) * 64; r0 = (t >> 4) * 64;
  }
  __shared__ float tile[64][65];
  int tr = threadIdx.x >> 4, tc = (threadIdx.x & 15) * 4;
#pragma unroll
  for (int p = 0; p < 4; p++) {
    int r = tr + p * 16;
    float4 v = *(const float4*)(in + (size_t)(r0 + r) * C + c0 + tc);
    tile[r][tc + 0] = v.x; tile[r][tc + 1] = v.y;
    tile[r][tc + 2] = v.z; tile[r][tc + 3] = v.w;
  }
  __syncthreads();
  int col = threadIdx.x >> 2;
  int rb  = (threadIdx.x & 3) * 8;
  unsigned short* ob = out + (size_t)(c0 + col) * R + r0;
#pragma unroll
  for (int j = 0; j < 2; j++) {
    int r8 = rb + j * 32;
    uint4 o;
    o.x = (unsigned int)f2bf(tile[r8 + 0][col]) | ((unsigned int)f2bf(tile[r8 + 1][col]) << 16);
    o.y = (unsigned int)f2bf(tile[r8 + 2][col]) | ((unsigned int)f2bf(tile[r8 + 3][col]) << 16);
    o.z = (unsigned int)f2bf(tile[r8 + 4][col]) | ((unsigned int)f2bf(tile[r8 + 5][col]) << 16);
    o.w = (unsigned int)f2bf(tile[r8 + 6][col]) | ((unsigned int)f2bf(tile[r8 + 7][col]) << 16);
    *(uint4*)(ob + r8) = o;
  }
}

// ------- scan (1 wave): 128-aligned offsets + tile table (<=72 tiles) ---------
__global__ void scan_k(int* ctrl) {
  int lane = threadIdx.x;
  int c = (lane < 8) ? ctrl[lane] : 0;
  int tiles = (c + 127) >> 7;
  int x = tiles;
  for (int d = 1; d < 8; d <<= 1) {
    int y = __shfl_up(x, d);
    if (lane >= d) x += y;
  }
  int excl = x - tiles;
  if (lane < 8) {
    ctrl[8 + lane]  = excl * 128;
    ctrl[17 + lane] = excl * 128;
  }
  int tot = __shfl(x, 7);
  if (lane == 0) { ctrl[25] = tot; ctrl[16] = tot * 128; }
  int ex[8], tl[8];
#pragma unroll
  for (int e = 0; e < 8; e++) { ex[e] = __shfl(excl, e); tl[e] = __shfl(tiles, e); }
  for (int i = lane; i < tot; i += 64) {
    int myE = 0;
#pragma unroll
    for (int e = 0; e < 8; e++) if (i >= ex[e] && i < ex[e] + tl[e]) myE = e;
    ctrl[32 + 2 * i] = myE;
    ctrl[33 + 2 * i] = i * 128;
  }
}

// ------- assign: wave-aggregated routing (8 atomics/wave) ---------------------
__global__ __launch_bounds__(256) void assign_k(
    const int* __restrict__ t2i, int* __restrict__ ctrl, int* __restrict__ row_map) {
  int g = blockIdx.x * 256 + threadIdx.x;
  int lane = threadIdx.x & 63;
  int e = t2i[g];
  int row = 0;
#pragma unroll
  for (int ee = 0; ee < E_NUM; ee++) {
    unsigned long long mask = __ballot(e == ee);
    if (e == ee) {
      int leader = __ffsll((long long)mask) - 1;
      int cnt = __popcll(mask);
      int rank = __popcll(mask & ((lane == 63) ? ~0ull >> 1 << 1 >> 1 | ((1ull << 63) - 1) & ((1ull << lane) - 1) : ((1ull << lane) - 1)));
      int base = 0;
      if (lane == leader) base = atomicAdd(&ctrl[17 + ee], cnt);
      base = __shfl(base, leader);
      row = base + rank;
    }
  }
  row_map[g] = row;
}

// ---------------- gcopy: x row -> bf16 row at row_map position ----------------
__global__ __launch_bounds__(128) void gcopy_k(
    const float* __restrict__ x, const int* __restrict__ row_map,
    unsigned short* __restrict__ xg) {
  int bid = blockIdx.x;
  int row = row_map[bid];
  int t = bid >> 1;
  const float* src = x + (size_t)t * H_DIM + threadIdx.x * 8;
  unsigned short* dst = xg + (size_t)row * H_DIM + threadIdx.x * 8;
  float4 v0 = *(const float4*)src;
  float4 v1 = *(const float4*)(src + 4);
  uint4 o;
  o.x = (unsigned int)f2bf(v0.x) | ((unsigned int)f2bf(v0.y) << 16);
  o.y = (unsigned int)f2bf(v0.z) | ((unsigned int)f2bf(v0.w) << 16);
  o.z = (unsigned int)f2bf(v1.x) | ((unsigned int)f2bf(v1.y) << 16);
  o.w = (unsigned int)f2bf(v1.z) | ((unsigned int)f2bf(v1.w) << 16);
  *(uint4*)dst = o;
}

// ======= grouped BT GEMM: 128x128 tile, BK=64, 4 waves (2x2), 2 blocks/CU =====
// r13-proven (115us). LDS (64KB): 2 buffers x {A[128][64] | B[128][64]} bf16,
// XOR-swizzled octets: unit(16B) = row*8 + (koct ^ (row&7)).
// Loop: {16 ds_read -> lgkmcnt(0) -> BAR -> 8 STG(t+2, cur buf dead) ->
// 32 MFMA (setprio) -> vmcnt(8) -> BAR}.  vmcnt never 0.
#define BAR() do { __builtin_amdgcn_sched_barrier(0); \
                   __builtin_amdgcn_s_barrier(); \
                   __builtin_amdgcn_sched_barrier(0); } while (0)

#define STG(gbase, kt, ebase, c) \
  async16((gbase) + (size_t)((c) * 32 + srcRow) * Kstr + (kt) + srcK8, \
          lds + (ebase) + (c) * 2048 + tid * 8)

#define LDU(ebase, row, koct) \
  (*(const bf16x8*)(lds + (ebase) + (((row) * 8 + ((koct) ^ ((row) & 7))) * 8)))

template <int MAP, bool RELU, bool OUTF32>
__global__ __launch_bounds__(256, 2) void gemm128_k(
    const int* __restrict__ ctrl, const unsigned short* __restrict__ A,
    const unsigned short* __restrict__ Bw, const float* __restrict__ bias,
    void* __restrict__ Cout, int Kstr, int N) {
  __shared__ unsigned short lds[32768];
  const int bid = blockIdx.x;
  int rt, bx;
  if (MAP == 1) {
    int wg = (bid & 7) * 288 + (bid >> 3);
    rt = wg >> 5; bx = wg & 31;
  } else {
    int wg = (bid & 7) * 72 + (bid >> 3);
    rt = wg >> 3; bx = wg & 7;
  }
  if (rt >= ctrl[25]) return;
  const int e    = ctrl[32 + 2 * rt];
  const int row0 = ctrl[33 + 2 * rt];
  const unsigned short* Ae = A + (size_t)row0 * Kstr;
  const unsigned short* Be = Bw + (size_t)e * ((size_t)N * Kstr) + (size_t)bx * 128 * Kstr;
  const int tid = threadIdx.x, lane = tid & 63;
  const int wid = tid >> 6, wm = wid >> 1, wn = wid & 1;
  const int lr = lane & 15, klane = lane >> 4;
  const int srcRow = tid >> 3;
  const int srcK8  = ((tid & 7) ^ (srcRow & 7)) * 8;
  const int NT = Kstr >> 6;

  f32x4 acc[4][4];
  f32x4 zero4 = {0.f, 0.f, 0.f, 0.f};
#pragma unroll
  for (int m = 0; m < 4; m++)
#pragma unroll
    for (int n = 0; n < 4; n++) acc[m][n] = zero4;

  {
    STG(Ae, 0, 0, 0); STG(Ae, 0, 0, 1); STG(Ae, 0, 0, 2); STG(Ae, 0, 0, 3);
    STG(Be, 0, 8192, 0); STG(Be, 0, 8192, 1); STG(Be, 0, 8192, 2); STG(Be, 0, 8192, 3);
    STG(Ae, 64, 16384, 0); STG(Ae, 64, 16384, 1); STG(Ae, 64, 16384, 2); STG(Ae, 64, 16384, 3);
    STG(Be, 64, 24576, 0); STG(Be, 64, 24576, 1); STG(Be, 64, 24576, 2); STG(Be, 64, 24576, 3);
    asm volatile("s_waitcnt vmcnt(8)" ::: "memory");
    BAR();
  }

  for (int t = 0; t < NT; t++) {
    const int cur = t & 1;
    const int abase = cur * 16384;
    const int bbase = abase + 8192;
    const int kt2 = min(t + 2, NT - 1) * 64;
    bf16x8 a[4][2], b[4][2];
#pragma unroll
    for (int m = 0; m < 4; m++) {
      int ar = wm * 64 + m * 16 + lr;
      a[m][0] = LDU(abase, ar, klane);
      a[m][1] = LDU(abase, ar, 4 + klane);
    }
#pragma unroll
    for (int n = 0; n < 4; n++) {
      int br = wn * 64 + n * 16 + lr;
      b[n][0] = LDU(bbase, br, klane);
      b[n][1] = LDU(bbase, br, 4 + klane);
    }
    asm volatile("s_waitcnt lgkmcnt(0)" ::: "memory");
    BAR();
    STG(Ae, kt2, abase, 0); STG(Ae, kt2, abase, 1);
    STG(Ae, kt2, abase, 2); STG(Ae, kt2, abase, 3);
    STG(Be, kt2, bbase, 0); STG(Be, kt2, bbase, 1);
    STG(Be, kt2, bbase, 2); STG(Be, kt2, bbase, 3);
    __builtin_amdgcn_s_setprio(1);
#pragma unroll
    for (int m = 0; m < 4; m++)
#pragma unroll
      for (int n = 0; n < 4; n++) {
        acc[m][n] = __builtin_amdgcn_mfma_f32_16x16x32_bf16(a[m][0], b[n][0], acc[m][n], 0, 0, 0);
        acc[m][n] = __builtin_amdgcn_mfma_f32_16x16x32_bf16(a[m][1], b[n][1], acc[m][n], 0, 0, 0);
      }
    __builtin_amdgcn_s_setprio(0);
    asm volatile("s_waitcnt vmcnt(8)" ::: "memory");
    BAR();
  }

  const int n0 = bx * 128;
  const float* be = bias + (size_t)e * N;
#pragma unroll
  for (int m = 0; m < 4; m++) {
#pragma unroll
    for (int q2 = 0; q2 < 4; q2++) {
      size_t ro = (size_t)(row0 + wm * 64 + m * 16 + (lane >> 4) * 4 + q2) * N;
#pragma unroll
      for (int n = 0; n < 4; n++) {
        int col = n0 + wn * 64 + n * 16 + lr;
        float v = acc[m][n][q2] + be[col];
        if (RELU) v = fmaxf(v, 0.f);
        if (OUTF32) ((float*)Cout)[ro + col] = v;
        else ((unsigned short*)Cout)[ro + col] = f2bf(v);
      }
    }
  }
}

// ---------------- combine: out[t] = w0*y[r0] + w1*y[r1] ----------------------
__global__ __launch_bounds__(256) void combine_k(
    const float* __restrict__ y, const int* __restrict__ row_map,
    const float* __restrict__ t2w, float* __restrict__ out) {
  int t = blockIdx.x;
  int i = threadIdx.x * 4;
  int r0 = row_map[2 * t], r1 = row_map[2 * t + 1];
  float w0 = t2w[2 * t], w1 = t2w[2 * t + 1];
  float4 a = *(const float4*)(y + (size_t)r0 * H_DIM + i);
  float4 b = *(const float4*)(y + (size_t)r1 * H_DIM + i);
  float4 o;
  o.x = w0 * a.x + w1 * b.x;
  o.y = w0 * a.y + w1 * b.y;
  o.z = w0 * a.z + w1 * b.z;
  o.w = w0 * a.w + w1 * b.w;
  *(float4*)(out + (size_t)t * H_DIM + i) = o;
}

extern "C" void kernel_launch(void* const* d_in, const int* in_sizes, int n_in,
                              void* d_out, int out_size, void* d_ws, size_t ws_size,
                              hipStream_t stream) {
  const float* x  = (const float*)d_in[0];
  const float* Wr = (const float*)d_in[1];
  const float* br = (const float*)d_in[2];
  const float* W1 = (const float*)d_in[3];
  const float* b1 = (const float*)d_in[4];
  const float* W2 = (const float*)d_in[5];
  const float* b2 = (const float*)d_in[6];
  float* out = (float*)d_out;

  char* ws = (char*)d_ws;
  int*   ctrl    = (int*)ws;
  int*   t2i     = (int*)(ws + 4096);
  float* t2w     = (float*)(ws + 4096 + 32768);
  int*   row_map = (int*)(ws + 4096 + 65536);
  size_t off = (size_t)1 << 20;
  unsigned short* WT1 = (unsigned short*)(ws + off); off += (size_t)E_NUM * F_DIM * H_DIM * 2;
  unsigned short* WT2 = (unsigned short*)(ws + off); off += (size_t)E_NUM * H_DIM * F_DIM * 2;
  unsigned short* xg  = (unsigned short*)(ws + off); off += (size_t)R_CAP * H_DIM * 2;
  unsigned short* hb  = (unsigned short*)(ws + off); off += (size_t)R_CAP * F_DIM * 2;
  float*          yb  = (float*)(ws + off);          off += (size_t)R_CAP * H_DIM * 4;

  if (ws_size < off) {
    hipMemsetAsync(d_out, 0, (size_t)out_size * 4, stream);
    return;
  }

  hipMemsetAsync(ctrl, 0, 4096, stream);   // before merged kernel: router atomics
  // merged: W transpose/cvt (16384 blocks) || router (1024 blocks)
  prep_router_k<<<dim3(17408), 256, 0, stream>>>(
      W1, W2, WT1, WT2, x, Wr, br, ctrl, t2i, t2w);
  scan_k<<<dim3(1), 64, 0, stream>>>(ctrl);
  assign_k<<<dim3(R_TOT / 256), 256, 0, stream>>>(t2i, ctrl, row_map);
  gcopy_k<<<dim3(R_TOT), 128, 0, stream>>>(x, row_map, xg);
  gemm128_k<1, true, false><<<dim3(2304), 256, 0, stream>>>(
      ctrl, xg, WT1, b1, hb, H_DIM, F_DIM);
  gemm128_k<2, false, true><<<dim3(576), 256, 0, stream>>>(
      ctrl, hb, WT2, b2, yb, F_DIM, H_DIM);
  combine_k<<<dim3(T_TOK), 256, 0, stream>>>(yb, row_map, t2w, out);
}

// Round 17
// 390.119 us; speedup vs baseline: 1.1541x; 1.0383x over previous
//
#include <hip/hip_runtime.h>

// MoE top-2 of 8 experts. T=4096, H=1024, F=4096.
// memset(ctrl) -> prep+router merged (router FIRST, hides under transpose) ->
// scan -> assign -> gcopy -> GEMM1(relu) -> GEMM2 -> combine.
// GEMM parked (r13, ~115us each). Transpose write pass emits full 128B lines.
#define T_TOK 4096
#define H_DIM 1024
#define F_DIM 4096
#define E_NUM 8
#define R_TOT 8192
#define NT_MAX 72
#define R_CAP (NT_MAX * 128)   // 9216 rows

typedef short bf16x8 __attribute__((ext_vector_type(8)));
typedef float f32x4 __attribute__((ext_vector_type(4)));

__device__ inline unsigned short f2bf(float f) {   // RNE f32 -> bf16
  unsigned int u = __builtin_bit_cast(unsigned int, f);
  return (unsigned short)((u + 0x7FFFu + ((u >> 16) & 1u)) >> 16);
}

__device__ inline void async16(const void* g, void* l) {
  __builtin_amdgcn_global_load_lds((const __attribute__((address_space(1))) void*)g,
                                   (__attribute__((address_space(3))) void*)l, 16, 0, 0);
}

// ------- prep+router merged: bid<1024 router (scheduled FIRST), else transpose.
// Transpose: fp32 tile[64][65]; read pass col=tid>>3, r8=(tid&7)*8 ->
// bank ((l&7)*8+i+(l>>3))%32 = all 32 banks 2-way (free); writes 8 lanes x
// 16B = full 128B line per column.
__global__ __launch_bounds__(256) void prep_router_k(
    const float* __restrict__ W1, const float* __restrict__ W2,
    unsigned short* __restrict__ WT1, unsigned short* __restrict__ WT2,
    const float* __restrict__ x, const float* __restrict__ Wr,
    const float* __restrict__ br, int* __restrict__ ctrl,
    int* __restrict__ t2i, float* __restrict__ t2w) {
  int bid = blockIdx.x;
  if (bid < 1024) {
    // ---------------- router path (first: hides under transpose stream) -----
    int lane = threadIdx.x & 63;
    int wid  = threadIdx.x >> 6;
    int t = bid * 4 + wid;
    const float* xr = x + (size_t)t * H_DIM;
    double acc[E_NUM];
#pragma unroll
    for (int e = 0; e < E_NUM; e++) acc[e] = 0.0;
    for (int i = lane; i < H_DIM; i += 64) {
      float xv = xr[i];
      const float* wr = Wr + (size_t)i * E_NUM;
      float4 w0 = *(const float4*)wr;
      float4 w1 = *(const float4*)(wr + 4);
      acc[0] += (double)xv * w0.x; acc[1] += (double)xv * w0.y;
      acc[2] += (double)xv * w0.z; acc[3] += (double)xv * w0.w;
      acc[4] += (double)xv * w1.x; acc[5] += (double)xv * w1.y;
      acc[6] += (double)xv * w1.z; acc[7] += (double)xv * w1.w;
    }
#pragma unroll
    for (int e = 0; e < E_NUM; e++) {
      double v = acc[e];
      for (int off = 32; off > 0; off >>= 1) v += __shfl_down(v, off);
      acc[e] = v;
    }
    if (lane == 0) {
      float l[E_NUM];
#pragma unroll
      for (int e = 0; e < E_NUM; e++) l[e] = (float)acc[e] + br[e];
      int ia = 0; float la = l[0];
#pragma unroll
      for (int e = 1; e < E_NUM; e++) if (l[e] > la) { la = l[e]; ia = e; }
      int ib = -1; float lb = -3.4e38f;
#pragma unroll
      for (int e = 0; e < E_NUM; e++) if (e != ia && l[e] > lb) { lb = l[e]; ib = e; }
      float w0 = 1.f / (1.f + __expf(lb - la));
      float w1 = 1.f - w0;
      t2i[2 * t] = ia; t2i[2 * t + 1] = ib;
      t2w[2 * t] = w0; t2w[2 * t + 1] = w1;
      atomicAdd(&ctrl[ia], 1);
      atomicAdd(&ctrl[ib], 1);
    }
    return;
  }
  // ---------------- transpose path ----------------
  int b2 = bid - 1024;
  size_t mat = (size_t)H_DIM * F_DIM;
  const float* in; unsigned short* out; int R, C, c0, r0;
  if (b2 < 8192) {
    int e = b2 >> 10, t = b2 & 1023;
    in = W1 + e * mat; out = WT1 + e * mat; R = H_DIM; C = F_DIM;
    c0 = (t & 63) * 64; r0 = (t >> 6) * 64;
  } else {
    int b3 = b2 - 8192;
    int e = b3 >> 10, t = b3 & 1023;
    in = W2 + e * mat; out = WT2 + e * mat; R = F_DIM; C = H_DIM;
    c0 = (t & 15) * 64; r0 = (t >> 4) * 64;
  }
  __shared__ float tile[64][65];
  int tr = threadIdx.x >> 4, tc = (threadIdx.x & 15) * 4;
#pragma unroll
  for (int p = 0; p < 4; p++) {
    int r = tr + p * 16;
    float4 v = *(const float4*)(in + (size_t)(r0 + r) * C + c0 + tc);
    tile[r][tc + 0] = v.x; tile[r][tc + 1] = v.y;
    tile[r][tc + 2] = v.z; tile[r][tc + 3] = v.w;
  }
  __syncthreads();
  int colb = threadIdx.x >> 3;        // 0..31
  int r8   = (threadIdx.x & 7) * 8;   // 0..56: 8 lanes x 16B = 128B per column
#pragma unroll
  for (int p = 0; p < 2; p++) {
    int col = colb + p * 32;
    uint4 o;
    o.x = (unsigned int)f2bf(tile[r8 + 0][col]) | ((unsigned int)f2bf(tile[r8 + 1][col]) << 16);
    o.y = (unsigned int)f2bf(tile[r8 + 2][col]) | ((unsigned int)f2bf(tile[r8 + 3][col]) << 16);
    o.z = (unsigned int)f2bf(tile[r8 + 4][col]) | ((unsigned int)f2bf(tile[r8 + 5][col]) << 16);
    o.w = (unsigned int)f2bf(tile[r8 + 6][col]) | ((unsigned int)f2bf(tile[r8 + 7][col]) << 16);
    *(uint4*)(out + (size_t)(c0 + col) * R + r0 + r8) = o;
  }
}

// ------- scan (1 wave): 128-aligned offsets + tile table (<=72 tiles) ---------
__global__ void scan_k(int* ctrl) {
  int lane = threadIdx.x;
  int c = (lane < 8) ? ctrl[lane] : 0;
  int tiles = (c + 127) >> 7;
  int x = tiles;
  for (int d = 1; d < 8; d <<= 1) {
    int y = __shfl_up(x, d);
    if (lane >= d) x += y;
  }
  int excl = x - tiles;
  if (lane < 8) {
    ctrl[8 + lane]  = excl * 128;
    ctrl[17 + lane] = excl * 128;
  }
  int tot = __shfl(x, 7);
  if (lane == 0) { ctrl[25] = tot; ctrl[16] = tot * 128; }
  int ex[8], tl[8];
#pragma unroll
  for (int e = 0; e < 8; e++) { ex[e] = __shfl(excl, e); tl[e] = __shfl(tiles, e); }
  for (int i = lane; i < tot; i += 64) {
    int myE = 0;
#pragma unroll
    for (int e = 0; e < 8; e++) if (i >= ex[e] && i < ex[e] + tl[e]) myE = e;
    ctrl[32 + 2 * i] = myE;
    ctrl[33 + 2 * i] = i * 128;
  }
}

// ------- assign: wave-aggregated routing (8 atomics/wave) ---------------------
__global__ __launch_bounds__(256) void assign_k(
    const int* __restrict__ t2i, int* __restrict__ ctrl, int* __restrict__ row_map) {
  int g = blockIdx.x * 256 + threadIdx.x;
  int lane = threadIdx.x & 63;
  int e = t2i[g];
  int row = 0;
#pragma unroll
  for (int ee = 0; ee < E_NUM; ee++) {
    unsigned long long mask = __ballot(e == ee);
    if (e == ee) {
      int leader = __ffsll((long long)mask) - 1;
      int cnt = __popcll(mask);
      int rank = __popcll(mask & ((lane == 63) ? ~0ull >> 1 << 1 >> 1 | ((1ull << 63) - 1) & ((1ull << lane) - 1) : ((1ull << lane) - 1)));
      int base = 0;
      if (lane == leader) base = atomicAdd(&ctrl[17 + ee], cnt);
      base = __shfl(base, leader);
      row = base + rank;
    }
  }
  row_map[g] = row;
}

// ---------------- gcopy: x row -> bf16 row at row_map position ----------------
__global__ __launch_bounds__(128) void gcopy_k(
    const float* __restrict__ x, const int* __restrict__ row_map,
    unsigned short* __restrict__ xg) {
  int bid = blockIdx.x;
  int row = row_map[bid];
  int t = bid >> 1;
  const float* src = x + (size_t)t * H_DIM + threadIdx.x * 8;
  unsigned short* dst = xg + (size_t)row * H_DIM + threadIdx.x * 8;
  float4 v0 = *(const float4*)src;
  float4 v1 = *(const float4*)(src + 4);
  uint4 o;
  o.x = (unsigned int)f2bf(v0.x) | ((unsigned int)f2bf(v0.y) << 16);
  o.y = (unsigned int)f2bf(v0.z) | ((unsigned int)f2bf(v0.w) << 16);
  o.z = (unsigned int)f2bf(v1.x) | ((unsigned int)f2bf(v1.y) << 16);
  o.w = (unsigned int)f2bf(v1.z) | ((unsigned int)f2bf(v1.w) << 16);
  *(uint4*)dst = o;
}

// ======= grouped BT GEMM: 128x128 tile, BK=64, 4 waves (2x2), 2 blocks/CU =====
// r13-proven (115us) — PARKED.
#define BAR() do { __builtin_amdgcn_sched_barrier(0); \
                   __builtin_amdgcn_s_barrier(); \
                   __builtin_amdgcn_sched_barrier(0); } while (0)

#define STG(gbase, kt, ebase, c) \
  async16((gbase) + (size_t)((c) * 32 + srcRow) * Kstr + (kt) + srcK8, \
          lds + (ebase) + (c) * 2048 + tid * 8)

#define LDU(ebase, row, koct) \
  (*(const bf16x8*)(lds + (ebase) + (((row) * 8 + ((koct) ^ ((row) & 7))) * 8)))

template <int MAP, bool RELU, bool OUTF32>
__global__ __launch_bounds__(256, 2) void gemm128_k(
    const int* __restrict__ ctrl, const unsigned short* __restrict__ A,
    const unsigned short* __restrict__ Bw, const float* __restrict__ bias,
    void* __restrict__ Cout, int Kstr, int N) {
  __shared__ unsigned short lds[32768];
  const int bid = blockIdx.x;
  int rt, bx;
  if (MAP == 1) {
    int wg = (bid & 7) * 288 + (bid >> 3);
    rt = wg >> 5; bx = wg & 31;
  } else {
    int wg = (bid & 7) * 72 + (bid >> 3);
    rt = wg >> 3; bx = wg & 7;
  }
  if (rt >= ctrl[25]) return;
  const int e    = ctrl[32 + 2 * rt];
  const int row0 = ctrl[33 + 2 * rt];
  const unsigned short* Ae = A + (size_t)row0 * Kstr;
  const unsigned short* Be = Bw + (size_t)e * ((size_t)N * Kstr) + (size_t)bx * 128 * Kstr;
  const int tid = threadIdx.x, lane = tid & 63;
  const int wid = tid >> 6, wm = wid >> 1, wn = wid & 1;
  const int lr = lane & 15, klane = lane >> 4;
  const int srcRow = tid >> 3;
  const int srcK8  = ((tid & 7) ^ (srcRow & 7)) * 8;
  const int NT = Kstr >> 6;

  f32x4 acc[4][4];
  f32x4 zero4 = {0.f, 0.f, 0.f, 0.f};
#pragma unroll
  for (int m = 0; m < 4; m++)
#pragma unroll
    for (int n = 0; n < 4; n++) acc[m][n] = zero4;

  {
    STG(Ae, 0, 0, 0); STG(Ae, 0, 0, 1); STG(Ae, 0, 0, 2); STG(Ae, 0, 0, 3);
    STG(Be, 0, 8192, 0); STG(Be, 0, 8192, 1); STG(Be, 0, 8192, 2); STG(Be, 0, 8192, 3);
    STG(Ae, 64, 16384, 0); STG(Ae, 64, 16384, 1); STG(Ae, 64, 16384, 2); STG(Ae, 64, 16384, 3);
    STG(Be, 64, 24576, 0); STG(Be, 64, 24576, 1); STG(Be, 64, 24576, 2); STG(Be, 64, 24576, 3);
    asm volatile("s_waitcnt vmcnt(8)" ::: "memory");
    BAR();
  }

  for (int t = 0; t < NT; t++) {
    const int cur = t & 1;
    const int abase = cur * 16384;
    const int bbase = abase + 8192;
    const int kt2 = min(t + 2, NT - 1) * 64;
    bf16x8 a[4][2], b[4][2];
#pragma unroll
    for (int m = 0; m < 4; m++) {
      int ar = wm * 64 + m * 16 + lr;
      a[m][0] = LDU(abase, ar, klane);
      a[m][1] = LDU(abase, ar, 4 + klane);
    }
#pragma unroll
    for (int n = 0; n < 4; n++) {
      int br = wn * 64 + n * 16 + lr;
      b[n][0] = LDU(bbase, br, klane);
      b[n][1] = LDU(bbase, br, 4 + klane);
    }
    asm volatile("s_waitcnt lgkmcnt(0)" ::: "memory");
    BAR();
    STG(Ae, kt2, abase, 0); STG(Ae, kt2, abase, 1);
    STG(Ae, kt2, abase, 2); STG(Ae, kt2, abase, 3);
    STG(Be, kt2, bbase, 0); STG(Be, kt2, bbase, 1);
    STG(Be, kt2, bbase, 2); STG(Be, kt2, bbase, 3);
    __builtin_amdgcn_s_setprio(1);
#pragma unroll
    for (int m = 0; m < 4; m++)
#pragma unroll
      for (int n = 0; n < 4; n++) {
        acc[m][n] = __builtin_amdgcn_mfma_f32_16x16x32_bf16(a[m][0], b[n][0], acc[m][n], 0, 0, 0);
        acc[m][n] = __builtin_amdgcn_mfma_f32_16x16x32_bf16(a[m][1], b[n][1], acc[m][n], 0, 0, 0);
      }
    __builtin_amdgcn_s_setprio(0);
    asm volatile("s_waitcnt vmcnt(8)" ::: "memory");
    BAR();
  }

  const int n0 = bx * 128;
  const float* be = bias + (size_t)e * N;
#pragma unroll
  for (int m = 0; m < 4; m++) {
#pragma unroll
    for (int q2 = 0; q2 < 4; q2++) {
      size_t ro = (size_t)(row0 + wm * 64 + m * 16 + (lane >> 4) * 4 + q2) * N;
#pragma unroll
      for (int n = 0; n < 4; n++) {
        int col = n0 + wn * 64 + n * 16 + lr;
        float v = acc[m][n][q2] + be[col];
        if (RELU) v = fmaxf(v, 0.f);
        if (OUTF32) ((float*)Cout)[ro + col] = v;
        else ((unsigned short*)Cout)[ro + col] = f2bf(v);
      }
    }
  }
}

// ---------------- combine: out[t] = w0*y[r0] + w1*y[r1] ----------------------
__global__ __launch_bounds__(256) void combine_k(
    const float* __restrict__ y, const int* __restrict__ row_map,
    const float* __restrict__ t2w, float* __restrict__ out) {
  int t = blockIdx.x;
  int i = threadIdx.x * 4;
  int r0 = row_map[2 * t], r1 = row_map[2 * t + 1];
  float w0 = t2w[2 * t], w1 = t2w[2 * t + 1];
  float4 a = *(const float4*)(y + (size_t)r0 * H_DIM + i);
  float4 b = *(const float4*)(y + (size_t)r1 * H_DIM + i);
  float4 o;
  o.x = w0 * a.x + w1 * b.x;
  o.y = w0 * a.y + w1 * b.y;
  o.z = w0 * a.z + w1 * b.z;
  o.w = w0 * a.w + w1 * b.w;
  *(float4*)(out + (size_t)t * H_DIM + i) = o;
}

extern "C" void kernel_launch(void* const* d_in, const int* in_sizes, int n_in,
                              void* d_out, int out_size, void* d_ws, size_t ws_size,
                              hipStream_t stream) {
  const float* x  = (const float*)d_in[0];
  const float* Wr = (const float*)d_in[1];
  const float* br = (const float*)d_in[2];
  const float* W1 = (const float*)d_in[3];
  const float* b1 = (const float*)d_in[4];
  const float* W2 = (const float*)d_in[5];
  const float* b2 = (const float*)d_in[6];
  float* out = (float*)d_out;

  char* ws = (char*)d_ws;
  int*   ctrl    = (int*)ws;
  int*   t2i     = (int*)(ws + 4096);
  float* t2w     = (float*)(ws + 4096 + 32768);
  int*   row_map = (int*)(ws + 4096 + 65536);
  size_t off = (size_t)1 << 20;
  unsigned short* WT1 = (unsigned short*)(ws + off); off += (size_t)E_NUM * F_DIM * H_DIM * 2;
  unsigned short* WT2 = (unsigned short*)(ws + off); off += (size_t)E_NUM * H_DIM * F_DIM * 2;
  unsigned short* xg  = (unsigned short*)(ws + off); off += (size_t)R_CAP * H_DIM * 2;
  unsigned short* hb  = (unsigned short*)(ws + off); off += (size_t)R_CAP * F_DIM * 2;
  float*          yb  = (float*)(ws + off);          off += (size_t)R_CAP * H_DIM * 4;

  if (ws_size < off) {
    hipMemsetAsync(d_out, 0, (size_t)out_size * 4, stream);
    return;
  }

  hipMemsetAsync(ctrl, 0, 4096, stream);   // before merged kernel: router atomics
  // merged: router (1024 blocks, FIRST) || W transpose/cvt (16384 blocks)
  prep_router_k<<<dim3(17408), 256, 0, stream>>>(
      W1, W2, WT1, WT2, x, Wr, br, ctrl, t2i, t2w);
  scan_k<<<dim3(1), 64, 0, stream>>>(ctrl);
  assign_k<<<dim3(R_TOT / 256), 256, 0, stream>>>(t2i, ctrl, row_map);
  gcopy_k<<<dim3(R_TOT), 128, 0, stream>>>(x, row_map, xg);
  gemm128_k<1, true, false><<<dim3(2304), 256, 0, stream>>>(
      ctrl, xg, WT1, b1, hb, H_DIM, F_DIM);
  gemm128_k<2, false, true><<<dim3(576), 256, 0, stream>>>(
      ctrl, hb, WT2, b2, yb, F_DIM, H_DIM);
  combine_k<<<dim3(T_TOK), 256, 0, stream>>>(yb, row_map, t2w, out);
}